// Round 2
// baseline (1252.893 us; speedup 1.0000x reference)
//
#include <hip/hip_runtime.h>

// Correlation layer: out[b, dy*9+dx, y, x] =
//   (1/256) * sum_c frn[b,c,y,x] * fqn_pad[b,c,y+dy,x+dx]   (pad r=4)
// Identity: dot(frn,fqn) = dot(fr,fq) * invnorm(fr) * invnorm(fq).
//
// R9: R8's static double-buffer + WAR fence before same-buffer STAGE.
// R8 analysis: vmcnt(9) math is sound (exactly 9 VMEM ops — 4 fr rolls +
// 5 other-buffer DMAs — are younger than the drained buffer's last DMA),
// but R8 exposed a WAR race R7's conservative compiler wait had masked:
// STAGE(A, ch+2) issues global_load_lds writes into A right after
// COMPUTE(A)'s ds_reads of A were ISSUED. ds_read completion (lgkm domain,
// ~120cy + bank-conflict queueing) vs DMA write-back (vm domain, ~200cy
// L2 hit) are unordered -> sporadic overwrite-before-read -> absmax 7.8e-4.
// Fix: sched_barrier + s_waitcnt lgkmcnt(0) + sched_barrier before each
// in-loop STAGE: all ds_reads of the buffer have COMPLETED before the DMA
// that overwrites it is issued. Nearly free: the FMAs consuming the ds_read
// data already force lgkm~0 by end of COMPUTE.
// Steady-state queue at each half-iteration's vmcnt(9) (oldest->newest):
//   [this buf's 5 DMAs][4 fr rolls][other buf's 5 DMAs] = 14 outstanding
//   -> vmcnt(9) drains exactly this buffer's DMAs, pipeline stays deep.
// DMA count stays runtime-uniform (5/half); OOB halo lanes CLAMP-addressed,
// zero-pad semantics enforced by the epilogue mask. 1 wave/block, 0 barriers.

#define BB 8
#define CC 256
#define HH 96
#define WW 128
#define HW (HH*WW)
#define CHW (CC*HW)
#define CKHW (CK*HW)
#define NDISP 81
#define TYS 4          // rows per wave-tile
#define HX4 18         // halo row width in float4 (72 floats = 64 + 8)
#define NSLOT (TYS*HX4) // 72 float4 slots per channel
#define CK 4           // channels per chunk
#define NCHK (CC/CK)   // 64 chunks
#define NST (NSLOT*CK) // 288 float4 slots per chunk
#define YT (HH/TYS)    // 24
#define XT 2
#define NTILES (BB*YT*XT) // 384
#define NGRP 9
#define EPSN 1e-12f

__device__ __forceinline__ void dma16(const void* g, void* l) {
    __builtin_amdgcn_global_load_lds(
        (const __attribute__((address_space(1))) void*)g,
        (__attribute__((address_space(3))) void*)l,
        16, 0, 0);
}

// Issue the 5 DMAs staging chunk CH of fq into SBUF (uniform count).
#define STAGE(SBUF, CH) do {                                              \
    const int _sco = (CH) * CKHW;                                         \
    _Pragma("unroll")                                                     \
    for (int _j = 0; _j < 4; ++_j)                                        \
        dma16(fq + soff[_j] + _sco, &SBUF[64 * _j]);                      \
    if (lane < 32)                                                        \
        dma16(fq + soff[4] + _sco, &SBUF[256]);                           \
} while (0)

// WAR fence: all ds_reads issued so far have COMPLETED (data in VGPRs)
// before any following global_load_lds may overwrite their source slots.
#define LDS_READS_DONE() do {                                             \
    __builtin_amdgcn_sched_barrier(0);                                    \
    asm volatile("s_waitcnt lgkmcnt(0)" ::: "memory");                    \
    __builtin_amdgcn_sched_barrier(0);                                    \
} while (0)

// Compute 4 channels from SBUF; roll fr registers to chunk NCH.
#define COMPUTE(SBUF, NCH) do {                                           \
    const int _nco = (NCH) * CKHW;                                        \
    _Pragma("unroll")                                                     \
    for (int _c = 0; _c < CK; ++_c) {                                     \
        float4 a = fra[_c];                                               \
        fra[_c] = *(const float4*)(fr + frbase + _nco + _c * HW);         \
        fr2.x += a.x * a.x; fr2.y += a.y * a.y;                           \
        fr2.z += a.z * a.z; fr2.w += a.w * a.w;                           \
        float rw[12];                                                     \
        _Pragma("unroll")                                                 \
        for (int _s4 = 0; _s4 < 3; ++_s4) {                               \
            float4 tq = SBUF[_c * NSLOT + ty * HX4 + tx + _s4];           \
            rw[_s4 * 4 + 0] = tq.x;                                       \
            rw[_s4 * 4 + 1] = tq.y;                                       \
            rw[_s4 * 4 + 2] = tq.z;                                       \
            rw[_s4 * 4 + 3] = tq.w;                                       \
        }                                                                 \
        _Pragma("unroll")                                                 \
        for (int _i = 0; _i < 12; ++_i) sqn[_i] += rw[_i] * rw[_i];       \
        _Pragma("unroll")                                                 \
        for (int _dx = 0; _dx < 9; ++_dx) {                               \
            acc[_dx].x += a.x * rw[_dx + 0];                              \
            acc[_dx].y += a.y * rw[_dx + 1];                              \
            acc[_dx].z += a.z * rw[_dx + 2];                              \
            acc[_dx].w += a.w * rw[_dx + 3];                              \
        }                                                                 \
    }                                                                     \
} while (0)

__global__ __launch_bounds__(64) __attribute__((amdgpu_waves_per_eu(4, 4)))
void corr_kernel(
    const float* __restrict__ fr, const float* __restrict__ fq,
    float* __restrict__ out)
{
    __shared__ float4 s_fqA[NST];   // even chunks (4608 B)
    __shared__ float4 s_fqB[NST];   // odd chunks  (4608 B)

    const int lane = threadIdx.x;
    const int tx   = lane & 15;    // 0..15, 4 px each
    const int ty   = lane >> 4;    // 0..3

    const int tile = blockIdx.x % NTILES;  // dy-copies at stride 384 ≡ 0 mod 8 → same XCD
    const int dy   = blockIdx.x / NTILES;  // 0..8
    const int b    = tile / (YT * XT);
    const int rem  = tile % (YT * XT);
    const int y0   = (rem >> 1) * TYS;
    const int x0   = (rem & 1) * 64;

    // ---- staging addresses: slot i = 64j+lane -> (c=i/72, row=(i%72)/18, col4=i%18)
    // OOB rows/cols clamped to valid addresses (garbage data; masked at epilogue).
    int soff[5];
#pragma unroll
    for (int j = 0; j < 5; ++j) {
        int i = 64 * j + lane;
        int c    = (i / NSLOT) & 3;   // &3: j=4 upper lanes never DMA'd, keep addr safe
        int s    = i % NSLOT;
        int row  = s / HX4;
        int col4 = s % HX4;
        int gy = y0 + dy - 4 + row;
        int gx = x0 - 4 + col4 * 4;
        gy = min(max(gy, 0), HH - 1);
        gx = min(max(gx, 0), WW - 4);   // stays 16B-aligned
        soff[j] = b * CHW + c * HW + gy * WW + gx;
    }

    const int frbase = b * CHW + (y0 + ty) * WW + x0 + tx * 4;

    // ---- preamble: DMA chunk 0 -> A, fr chunk 0 -> regs, DMA chunk 1 -> B
    STAGE(s_fqA, 0);

    float4 fra[CK];
#pragma unroll
    for (int c = 0; c < CK; ++c)
        fra[c] = *(const float4*)(fr + frbase + c * HW);

    STAGE(s_fqB, 1);

    float4 acc[9];
#pragma unroll
    for (int d = 0; d < 9; ++d) acc[d] = make_float4(0.f, 0.f, 0.f, 0.f);
    float sqn[12];
#pragma unroll
    for (int i = 0; i < 12; ++i) sqn[i] = 0.f;
    float4 fr2 = make_float4(0.f, 0.f, 0.f, 0.f);

#pragma unroll 1
    for (int t = 0; t < NCHK / 2; ++t) {
        // ---- half A: chunk 2t from s_fqA ----
        __builtin_amdgcn_s_waitcnt(0x0F79);   // vmcnt(9): drain A's 5 DMAs
        __builtin_amdgcn_sched_barrier(0);    // nothing hoists above the wait
        COMPUTE(s_fqA, 2 * t + 1);            // fr rolls to chunk 2t+1 (<= 63)
        LDS_READS_DONE();                     // A's ds_reads retired before overwrite
        STAGE(s_fqA, min(2 * t + 2, NCHK - 1));   // t=31: dead re-issue into A

        // ---- half B: chunk 2t+1 from s_fqB ----
        __builtin_amdgcn_s_waitcnt(0x0F79);   // vmcnt(9): drain B's 5 DMAs
        __builtin_amdgcn_sched_barrier(0);
        COMPUTE(s_fqB, min(2 * t + 2, NCHK - 1)); // t=31: dead fr re-load
        LDS_READS_DONE();                     // B's ds_reads retired before overwrite
        STAGE(s_fqB, min(2 * t + 3, NCHK - 1));   // t=31: dead re-issue into B
    }

    // drain dead-issued DMAs before LDS is freed at endpgm
    __builtin_amdgcn_s_waitcnt(0x0F70);   // vmcnt(0)

    // ---- epilogue: norms in registers + OOB mask (== reference zero-pad) ----
    float inq[12];
#pragma unroll
    for (int i = 0; i < 12; ++i)
        inq[i] = 1.0f / fmaxf(sqrtf(sqn[i]), EPSN);

    float4 ir;
    ir.x = 1.0f / fmaxf(sqrtf(fr2.x), EPSN);
    ir.y = 1.0f / fmaxf(sqrtf(fr2.y), EPSN);
    ir.z = 1.0f / fmaxf(sqrtf(fr2.z), EPSN);
    ir.w = 1.0f / fmaxf(sqrtf(fr2.w), EPSN);

    const bool rowok = ((unsigned)(y0 + ty + dy - 4) < (unsigned)HH);
    const int  xe0   = x0 + tx * 4;
    const float inv256 = 1.0f / 256.0f;
    const int obase = (b * NDISP + dy * 9) * HW + (y0 + ty) * WW + xe0;
#pragma unroll
    for (int dx = 0; dx < 9; ++dx) {
        float4 a = acc[dx];
        float4 o;
        o.x = a.x * ir.x * inq[dx + 0] * inv256;
        o.y = a.y * ir.y * inq[dx + 1] * inv256;
        o.z = a.z * ir.z * inq[dx + 2] * inv256;
        o.w = a.w * ir.w * inq[dx + 3] * inv256;
        const int cb = xe0 + dx - 4;   // fq column for px .x at this dx
        o.x = (rowok && (unsigned)(cb    ) < (unsigned)WW) ? o.x : 0.f;
        o.y = (rowok && (unsigned)(cb + 1) < (unsigned)WW) ? o.y : 0.f;
        o.z = (rowok && (unsigned)(cb + 2) < (unsigned)WW) ? o.z : 0.f;
        o.w = (rowok && (unsigned)(cb + 3) < (unsigned)WW) ? o.w : 0.f;
        *(float4*)(out + obase + dx * HW) = o;
    }
}

extern "C" void kernel_launch(void* const* d_in, const int* in_sizes, int n_in,
                              void* d_out, int out_size, void* d_ws, size_t ws_size,
                              hipStream_t stream) {
    const float* fr = (const float*)d_in[0];
    const float* fq = (const float*)d_in[1];
    float* out = (float*)d_out;
    corr_kernel<<<dim3(NTILES * NGRP), dim3(64), 0, stream>>>(fr, fq, out);
}

// Round 3
// 1211.345 us; speedup vs baseline: 1.0343x; 1.0343x over previous
//
#include <hip/hip_runtime.h>

// Correlation layer: out[b, dy*9+dx, y, x] =
//   (1/256) * sum_c frn[b,c,y,x] * fqn_pad[b,c,y+dy,x+dx]   (pad r=4)
// Identity: dot(frn,fqn) = dot(fr,fq) * invnorm(fr) * invnorm(fq).
//
// R10: R9 structure, fully SCALARIZED + no "memory" clobber.
// R9 counters: WRITE_SIZE 37MB->2.36GB, FETCH 270MB->2.18GB, VALUBusy 5%
// with VGPR_Count still 64 => not an allocator spill but compile-time
// DEMOTION of acc[]/rw[]/sqn[] to scratch (rule-#20 class: macro-ized
// _Pragma unroll + asm-with-memory-clobber between unrolled accesses left
// runtime-indexed array refs alive). ~2.4GB/dir scratch RMW traffic made
// the kernel HBM-bound on spills (dur ~= hbm_bytes / 4.1 TB/s).
// Fix: every per-thread array becomes NAMED scalars via token-paste macros
// (acc0..8, q0..11, sq0..11, fra0..3, so0..4) -- no alloca, nothing to
// demote. WAR fence keeps hardware lgkmcnt(0) (builtin, compiler-modeled)
// bracketed by sched_barrier(0); the "memory" clobber is dropped.
// Pipeline (unchanged from R9): static A/B LDS buffers, 2x-unrolled chunk
// loop; per half: vmcnt(9) -> compute -> lgkmcnt(0) -> STAGE next+2.
// Steady-state VMEM queue at each vmcnt(9) (oldest->newest):
//   [this buf's 5 DMAs][4 fr rolls][other buf's 5 DMAs] = 14 outstanding
//   -> vmcnt(9) drains exactly this buffer's DMAs, pipeline stays deep.
// DMA count runtime-uniform (5/half); OOB halo lanes CLAMP-addressed,
// zero-pad semantics enforced by the epilogue mask. 1 wave/block, 0 barriers.

#define BB 8
#define CC 256
#define HH 96
#define WW 128
#define HW (HH*WW)
#define CHW (CC*HW)
#define CKHW (CK*HW)
#define NDISP 81
#define TYS 4          // rows per wave-tile
#define HX4 18         // halo row width in float4 (72 floats = 64 + 8)
#define NSLOT (TYS*HX4) // 72 float4 slots per channel
#define CK 4           // channels per chunk
#define NCHK (CC/CK)   // 64 chunks
#define NST (NSLOT*CK) // 288 float4 slots per chunk
#define YT (HH/TYS)    // 24
#define XT 2
#define NTILES (BB*YT*XT) // 384
#define NGRP 9
#define EPSN 1e-12f

__device__ __forceinline__ void dma16(const void* g, void* l) {
    __builtin_amdgcn_global_load_lds(
        (const __attribute__((address_space(1))) void*)g,
        (__attribute__((address_space(3))) void*)l,
        16, 0, 0);
}

// Issue the 5 DMAs staging chunk CH of fq into SBUF (uniform count).
#define STAGE(SBUF, CH) do {                                              \
    const int _sco = (CH) * CKHW;                                         \
    dma16(fq + so0 + _sco, &SBUF[0]);                                     \
    dma16(fq + so1 + _sco, &SBUF[64]);                                    \
    dma16(fq + so2 + _sco, &SBUF[128]);                                   \
    dma16(fq + so3 + _sco, &SBUF[192]);                                   \
    if (lane < 32)                                                        \
        dma16(fq + so4 + _sco, &SBUF[256]);                               \
} while (0)

// One dx tap: acc{D} += a * q[D..D+3]
#define DX(D, R0, R1, R2, R3)                                             \
    acc##D.x += a.x * (R0); acc##D.y += a.y * (R1);                       \
    acc##D.z += a.z * (R2); acc##D.w += a.w * (R3);

// One channel C (literal 0..3) from SBUF; rolls fra{C} to offset NCO.
#define CHAN(SBUF, C, NCO) do {                                           \
    float4 a = fra##C;                                                    \
    fra##C = *(const float4*)(fr + frbase + (NCO) + (C) * HW);            \
    fr2.x += a.x * a.x; fr2.y += a.y * a.y;                               \
    fr2.z += a.z * a.z; fr2.w += a.w * a.w;                               \
    const float4 t0 = SBUF[(C) * NSLOT + lbase + 0];                      \
    const float4 t1 = SBUF[(C) * NSLOT + lbase + 1];                      \
    const float4 t2 = SBUF[(C) * NSLOT + lbase + 2];                      \
    const float q0 = t0.x, q1 = t0.y, q2  = t0.z, q3  = t0.w;             \
    const float q4 = t1.x, q5 = t1.y, q6  = t1.z, q7  = t1.w;             \
    const float q8 = t2.x, q9 = t2.y, q10 = t2.z, q11 = t2.w;             \
    sq0 += q0*q0;  sq1 += q1*q1;  sq2  += q2*q2;   sq3  += q3*q3;         \
    sq4 += q4*q4;  sq5 += q5*q5;  sq6  += q6*q6;   sq7  += q7*q7;         \
    sq8 += q8*q8;  sq9 += q9*q9;  sq10 += q10*q10; sq11 += q11*q11;       \
    DX(0, q0, q1, q2, q3)   DX(1, q1, q2, q3, q4)                         \
    DX(2, q2, q3, q4, q5)   DX(3, q3, q4, q5, q6)                         \
    DX(4, q4, q5, q6, q7)   DX(5, q5, q6, q7, q8)                         \
    DX(6, q6, q7, q8, q9)   DX(7, q7, q8, q9, q10)                        \
    DX(8, q8, q9, q10, q11)                                               \
} while (0)

// All 4 channels of the chunk resident in SBUF; fr rolls to chunk offset NCO.
#define COMPUTE(SBUF, NCO) do {                                           \
    const int _nco = (NCO);                                               \
    CHAN(SBUF, 0, _nco); CHAN(SBUF, 1, _nco);                             \
    CHAN(SBUF, 2, _nco); CHAN(SBUF, 3, _nco);                             \
} while (0)

// WAR fence: all ds_reads issued so far have completed (data in VGPRs)
// before any following global_load_lds may overwrite their source slots.
// lgkm is ~0 here anyway (FMA consumers already forced the waits).
#define LDS_READS_DONE() do {                                             \
    __builtin_amdgcn_sched_barrier(0);                                    \
    __builtin_amdgcn_s_waitcnt(0xC07F);  /* lgkmcnt(0) only */            \
    __builtin_amdgcn_sched_barrier(0);                                    \
} while (0)

// Staging address for DMA slot J (literal 0..4):
// slot i = 64*J + lane -> (c = i/72, row = (i%72)/18, col4 = i%18).
// OOB rows/cols clamped to valid addresses (garbage data; masked at epilogue).
#define SOFF(J) ({                                                        \
    const int _i   = 64 * (J) + lane;                                     \
    const int _c   = (_i / NSLOT) & 3;  /* J=4 upper lanes never DMA'd */ \
    const int _s   = _i % NSLOT;                                          \
    const int _row = _s / HX4;                                            \
    const int _col = _s % HX4;                                            \
    int _gy = y0 + dy - 4 + _row;                                         \
    int _gx = x0 - 4 + _col * 4;                                          \
    _gy = min(max(_gy, 0), HH - 1);                                       \
    _gx = min(max(_gx, 0), WW - 4);   /* stays 16B-aligned */             \
    b * CHW + _c * HW + _gy * WW + _gx;                                   \
})

#define OUTDX(D, I0, I1, I2, I3) do {                                     \
    float4 o;                                                             \
    o.x = acc##D.x * ir.x * (I0) * inv256;                                \
    o.y = acc##D.y * ir.y * (I1) * inv256;                                \
    o.z = acc##D.z * ir.z * (I2) * inv256;                                \
    o.w = acc##D.w * ir.w * (I3) * inv256;                                \
    const int cb = xe0 + (D) - 4;   /* fq column for px .x at this dx */  \
    o.x = (rowok && (unsigned)(cb    ) < (unsigned)WW) ? o.x : 0.f;       \
    o.y = (rowok && (unsigned)(cb + 1) < (unsigned)WW) ? o.y : 0.f;       \
    o.z = (rowok && (unsigned)(cb + 2) < (unsigned)WW) ? o.z : 0.f;       \
    o.w = (rowok && (unsigned)(cb + 3) < (unsigned)WW) ? o.w : 0.f;       \
    *(float4*)(out + obase + (D) * HW) = o;                               \
} while (0)

__global__ __launch_bounds__(64) __attribute__((amdgpu_waves_per_eu(4, 4)))
void corr_kernel(
    const float* __restrict__ fr, const float* __restrict__ fq,
    float* __restrict__ out)
{
    __shared__ float4 s_fqA[NST];   // even chunks (4608 B)
    __shared__ float4 s_fqB[NST];   // odd chunks  (4608 B)

    const int lane = threadIdx.x;
    const int tx   = lane & 15;    // 0..15, 4 px each
    const int ty   = lane >> 4;    // 0..3

    const int tile = blockIdx.x % NTILES;  // dy-copies at stride 384 ≡ 0 mod 8 → same XCD
    const int dy   = blockIdx.x / NTILES;  // 0..8
    const int b    = tile / (YT * XT);
    const int rem  = tile % (YT * XT);
    const int y0   = (rem >> 1) * TYS;
    const int x0   = (rem & 1) * 64;

    const int so0 = SOFF(0);
    const int so1 = SOFF(1);
    const int so2 = SOFF(2);
    const int so3 = SOFF(3);
    const int so4 = SOFF(4);

    const int frbase = b * CHW + (y0 + ty) * WW + x0 + tx * 4;
    const int lbase  = ty * HX4 + tx;

    // ---- preamble: DMA chunk 0 -> A, fr chunk 0 -> regs, DMA chunk 1 -> B
    STAGE(s_fqA, 0);

    float4 fra0 = *(const float4*)(fr + frbase + 0 * HW);
    float4 fra1 = *(const float4*)(fr + frbase + 1 * HW);
    float4 fra2 = *(const float4*)(fr + frbase + 2 * HW);
    float4 fra3 = *(const float4*)(fr + frbase + 3 * HW);

    STAGE(s_fqB, 1);

    float4 acc0 = make_float4(0.f, 0.f, 0.f, 0.f), acc1 = acc0, acc2 = acc0,
           acc3 = acc0, acc4 = acc0, acc5 = acc0, acc6 = acc0, acc7 = acc0,
           acc8 = acc0;
    float sq0 = 0.f, sq1 = 0.f, sq2 = 0.f, sq3 = 0.f, sq4 = 0.f, sq5 = 0.f,
          sq6 = 0.f, sq7 = 0.f, sq8 = 0.f, sq9 = 0.f, sq10 = 0.f, sq11 = 0.f;
    float4 fr2 = make_float4(0.f, 0.f, 0.f, 0.f);

#pragma unroll 1
    for (int t = 0; t < NCHK / 2; ++t) {
        // ---- half A: chunk 2t from s_fqA ----
        __builtin_amdgcn_s_waitcnt(0x0F79);   // vmcnt(9): drain A's 5 DMAs
        __builtin_amdgcn_sched_barrier(0);    // nothing hoists above the wait
        COMPUTE(s_fqA, (2 * t + 1) * CKHW);   // fr rolls to chunk 2t+1 (<=63)
        LDS_READS_DONE();                     // A's ds_reads retired before overwrite
        STAGE(s_fqA, min(2 * t + 2, NCHK - 1));   // t=31: dead re-issue into A

        // ---- half B: chunk 2t+1 from s_fqB ----
        __builtin_amdgcn_s_waitcnt(0x0F79);   // vmcnt(9): drain B's 5 DMAs
        __builtin_amdgcn_sched_barrier(0);
        COMPUTE(s_fqB, min(2 * t + 2, NCHK - 1) * CKHW); // t=31: dead fr re-load
        LDS_READS_DONE();                     // B's ds_reads retired before overwrite
        STAGE(s_fqB, min(2 * t + 3, NCHK - 1));   // t=31: dead re-issue into B
    }

    // drain dead-issued DMAs before LDS is freed at endpgm
    __builtin_amdgcn_s_waitcnt(0x0F70);   // vmcnt(0)

    // ---- epilogue: norms in registers + OOB mask (== reference zero-pad) ----
    const float iq0  = 1.0f / fmaxf(sqrtf(sq0),  EPSN);
    const float iq1  = 1.0f / fmaxf(sqrtf(sq1),  EPSN);
    const float iq2  = 1.0f / fmaxf(sqrtf(sq2),  EPSN);
    const float iq3  = 1.0f / fmaxf(sqrtf(sq3),  EPSN);
    const float iq4  = 1.0f / fmaxf(sqrtf(sq4),  EPSN);
    const float iq5  = 1.0f / fmaxf(sqrtf(sq5),  EPSN);
    const float iq6  = 1.0f / fmaxf(sqrtf(sq6),  EPSN);
    const float iq7  = 1.0f / fmaxf(sqrtf(sq7),  EPSN);
    const float iq8  = 1.0f / fmaxf(sqrtf(sq8),  EPSN);
    const float iq9  = 1.0f / fmaxf(sqrtf(sq9),  EPSN);
    const float iq10 = 1.0f / fmaxf(sqrtf(sq10), EPSN);
    const float iq11 = 1.0f / fmaxf(sqrtf(sq11), EPSN);

    float4 ir;
    ir.x = 1.0f / fmaxf(sqrtf(fr2.x), EPSN);
    ir.y = 1.0f / fmaxf(sqrtf(fr2.y), EPSN);
    ir.z = 1.0f / fmaxf(sqrtf(fr2.z), EPSN);
    ir.w = 1.0f / fmaxf(sqrtf(fr2.w), EPSN);

    const bool rowok = ((unsigned)(y0 + ty + dy - 4) < (unsigned)HH);
    const int  xe0   = x0 + tx * 4;
    const float inv256 = 1.0f / 256.0f;
    const int obase = (b * NDISP + dy * 9) * HW + (y0 + ty) * WW + xe0;

    OUTDX(0, iq0, iq1, iq2, iq3);
    OUTDX(1, iq1, iq2, iq3, iq4);
    OUTDX(2, iq2, iq3, iq4, iq5);
    OUTDX(3, iq3, iq4, iq5, iq6);
    OUTDX(4, iq4, iq5, iq6, iq7);
    OUTDX(5, iq5, iq6, iq7, iq8);
    OUTDX(6, iq6, iq7, iq8, iq9);
    OUTDX(7, iq7, iq8, iq9, iq10);
    OUTDX(8, iq8, iq9, iq10, iq11);
}

extern "C" void kernel_launch(void* const* d_in, const int* in_sizes, int n_in,
                              void* d_out, int out_size, void* d_ws, size_t ws_size,
                              hipStream_t stream) {
    const float* fr = (const float*)d_in[0];
    const float* fq = (const float*)d_in[1];
    float* out = (float*)d_out;
    corr_kernel<<<dim3(NTILES * NGRP), dim3(64), 0, stream>>>(fr, fq, out);
}

// Round 4
// 284.847 us; speedup vs baseline: 4.3985x; 4.2526x over previous
//
#include <hip/hip_runtime.h>

// Correlation layer: out[b, dy*9+dx, y, x] =
//   (1/256) * sum_c frn[b,c,y,x] * fqn_pad[b,c,y+dy,x+dx]   (pad r=4)
// Identity: dot(frn,fqn) = dot(fr,fq) * invnorm(fr) * invnorm(fq).
//
// R11: R7 skeleton EXACTLY (190us known-good; R8-R10's restructured
// pipeline produced a pathological 2.2GB symmetric-traffic mode twice and
// is abandoned), with dy-BATCHING 3-per-block to cut cache-fabric traffic.
// R7 re-diagnosis: 3456 blocks x 64 chunks x 8.6KB = 1.9GB moved from
// LLC/L2 to CUs in 190us = 10 TB/s sustained -- fabric-bandwidth-bound
// (HBM 20%, VALU 30%: the saturated pipe has no counter). Cause: 9x dy
// replication refetches fr and the fq halo per dy. Fix: each block handles
// dy = 3*dyg + {0,1,2}; staged rows per chunk 4 -> 6 (shared by the 3 dy):
// fq bytes x0.5, fr bytes /3 per dy-triple (2.4x less fabric traffic),
// compute per chunk x3 (self-hides latency at 2 waves/SIMD).
// Deltas vs R7: NDMA 5->7 (432 slots: 6 full + lane<48), vmcnt 9->11
// (outstanding at wait: this chunk's 7 + 4 fr + next 7 = 18 -> drain 7),
// acc/sqn/epilogue gain a g<3 dim, waves_per_eu (4,4)->(2,8) (~200 VGPR
// live; 128 budget would spill -> 256 budget, grid 1152 = 4.5 blk/CU all
// resident at 2 waves/SIMD). DMA count runtime-uniform (7/iter); OOB halo
// lanes CLAMP-addressed; zero-pad semantics via epilogue mask.
// 1 wave/block, 0 barriers.

#define BB 8
#define CC 256
#define HH 96
#define WW 128
#define HW (HH*WW)
#define CHW (CC*HW)
#define NDISP 81
#define TYS 4            // output rows per block
#define GD 3             // dy per block
#define HROWS (TYS+GD-1) // 6 staged rows per chunk-channel
#define HX4 18           // halo row width in float4 (72 floats = 64 + 8)
#define NSLOT (HROWS*HX4) // 108 float4 slots per channel
#define CK 4             // channels per chunk
#define CKHW (CK*HW)
#define NCHK (CC/CK)     // 64 chunks
#define NST (NSLOT*CK)   // 432 float4 slots per chunk
#define YT (HH/TYS)      // 24
#define XT 2
#define NTILES (BB*YT*XT) // 384
#define NGRP 3           // dy-groups
#define EPSN 1e-12f

__device__ __forceinline__ void dma16(const void* g, void* l) {
    __builtin_amdgcn_global_load_lds(
        (const __attribute__((address_space(1))) void*)g,
        (__attribute__((address_space(3))) void*)l,
        16, 0, 0);
}

__global__ __launch_bounds__(64) __attribute__((amdgpu_waves_per_eu(2, 8)))
void corr_kernel(
    const float* __restrict__ fr, const float* __restrict__ fq,
    float* __restrict__ out)
{
    __shared__ float4 s_fq[2][NST];   // 13824 B, double-buffered fq halo chunk

    const int lane = threadIdx.x;
    const int tx   = lane & 15;    // 0..15, 4 px each
    const int ty   = lane >> 4;    // 0..3

    const int tile = blockIdx.x % NTILES;  // dyg-copies at stride 384 ≡ 0 mod 8 → same XCD
    const int dyg  = blockIdx.x / NTILES;  // 0..2 → dy = 3*dyg + g
    const int b    = tile / (YT * XT);
    const int rem  = tile % (YT * XT);
    const int y0   = (rem >> 1) * TYS;
    const int x0   = (rem & 1) * 64;

    // ---- staging addresses: slot i = 64j+lane -> (c=i/108, row=(i%108)/18, col4=i%18)
    // OOB rows/cols clamped to valid addresses (garbage data; masked at epilogue).
    int soff[7];
#pragma unroll
    for (int j = 0; j < 7; ++j) {
        int i = 64 * j + lane;
        int c    = (i / NSLOT) & 3;   // &3: j=6 upper lanes never DMA'd, keep addr safe
        int s    = i % NSLOT;
        int row  = s / HX4;
        int col4 = s % HX4;
        int gy = y0 + 3 * dyg - 4 + row;
        int gx = x0 - 4 + col4 * 4;
        gy = min(max(gy, 0), HH - 1);
        gx = min(max(gx, 0), WW - 4);   // stays 16B-aligned
        soff[j] = b * CHW + c * HW + gy * WW + gx;
    }

    const int frbase = b * CHW + (y0 + ty) * WW + x0 + tx * 4;

    // ---- preamble: DMA chunk 0 -> buf0 (7 events), fr chunk 0 -> regs (4 events)
#pragma unroll
    for (int j = 0; j < 6; ++j)
        dma16(fq + soff[j], &s_fq[0][64 * j]);
    if (lane < 48)                       // 48 tail slots; exec never empty
        dma16(fq + soff[6], &s_fq[0][384]);

    float4 fra[CK];
#pragma unroll
    for (int c = 0; c < CK; ++c)
        fra[c] = *(const float4*)(fr + frbase + c * HW);

    float4 acc[GD][9];
#pragma unroll
    for (int g = 0; g < GD; ++g)
#pragma unroll
        for (int d = 0; d < 9; ++d) acc[g][d] = make_float4(0.f, 0.f, 0.f, 0.f);
    float sqn[GD][12];
#pragma unroll
    for (int g = 0; g < GD; ++g)
#pragma unroll
        for (int i = 0; i < 12; ++i) sqn[g][i] = 0.f;
    float4 fr2 = make_float4(0.f, 0.f, 0.f, 0.f);

#pragma unroll 1
    for (int ch = 0; ch < NCHK; ++ch) {
        const int p   = ch & 1;
        const int nch = (ch + 1 < NCHK) ? ch + 1 : ch;   // last iter: dead re-issue
        const int nco = nch * CKHW;                      // keeps vmcnt count uniform

        // ---- issue next chunk's 7 DMAs into the other buffer ----
#pragma unroll
        for (int j = 0; j < 6; ++j)
            dma16(fq + soff[j] + nco, &s_fq[1 - p][64 * j]);
        if (lane < 48)
            dma16(fq + soff[6] + nco, &s_fq[1 - p][384]);

        // Drain everything older than the 11 just/soon-issued next-chunk ops:
        // prev 7 DMA (this chunk's fq) done; prev 4 fr covered by reg deps.
        __builtin_amdgcn_s_waitcnt(0x0F7B);   // vmcnt(11), no lgkm/exp wait
        __builtin_amdgcn_sched_barrier(0);    // nothing hoists above the wait

        // ---- compute 4 channels x 3 dy from buf p; roll fr one chunk ahead ----
#pragma unroll
        for (int c = 0; c < CK; ++c) {
            float4 a = fra[c];
            fra[c] = *(const float4*)(fr + frbase + nco + c * HW);
            fr2.x += a.x * a.x; fr2.y += a.y * a.y;
            fr2.z += a.z * a.z; fr2.w += a.w * a.w;

#pragma unroll
            for (int g = 0; g < GD; ++g) {
                float rw[12];
#pragma unroll
                for (int s4 = 0; s4 < 3; ++s4) {
                    float4 t = s_fq[p][c * NSLOT + (ty + g) * HX4 + tx + s4];
                    rw[s4 * 4 + 0] = t.x;
                    rw[s4 * 4 + 1] = t.y;
                    rw[s4 * 4 + 2] = t.z;
                    rw[s4 * 4 + 3] = t.w;
                }
#pragma unroll
                for (int i = 0; i < 12; ++i) sqn[g][i] += rw[i] * rw[i];
#pragma unroll
                for (int dx = 0; dx < 9; ++dx) {
                    acc[g][dx].x += a.x * rw[dx + 0];
                    acc[g][dx].y += a.y * rw[dx + 1];
                    acc[g][dx].z += a.z * rw[dx + 2];
                    acc[g][dx].w += a.w * rw[dx + 3];
                }
            }
        }
    }

    // drain dead-issued DMAs before LDS is freed at endpgm
    __builtin_amdgcn_s_waitcnt(0x0F70);   // vmcnt(0)

    // ---- epilogue: norms in registers + OOB mask (== reference zero-pad) ----
    float4 ir;
    ir.x = 1.0f / fmaxf(sqrtf(fr2.x), EPSN);
    ir.y = 1.0f / fmaxf(sqrtf(fr2.y), EPSN);
    ir.z = 1.0f / fmaxf(sqrtf(fr2.z), EPSN);
    ir.w = 1.0f / fmaxf(sqrtf(fr2.w), EPSN);

    const int  xe0   = x0 + tx * 4;
    const float inv256 = 1.0f / 256.0f;

#pragma unroll
    for (int g = 0; g < GD; ++g) {
        const int dy = 3 * dyg + g;
        float inq[12];
#pragma unroll
        for (int i = 0; i < 12; ++i)
            inq[i] = 1.0f / fmaxf(sqrtf(sqn[g][i]), EPSN);

        const bool rowok = ((unsigned)(y0 + ty + dy - 4) < (unsigned)HH);
        const int obase = (b * NDISP + dy * 9) * HW + (y0 + ty) * WW + xe0;
#pragma unroll
        for (int dx = 0; dx < 9; ++dx) {
            float4 a = acc[g][dx];
            float4 o;
            o.x = a.x * ir.x * inq[dx + 0] * inv256;
            o.y = a.y * ir.y * inq[dx + 1] * inv256;
            o.z = a.z * ir.z * inq[dx + 2] * inv256;
            o.w = a.w * ir.w * inq[dx + 3] * inv256;
            const int cb = xe0 + dx - 4;   // fq column for px .x at this dx
            o.x = (rowok && (unsigned)(cb    ) < (unsigned)WW) ? o.x : 0.f;
            o.y = (rowok && (unsigned)(cb + 1) < (unsigned)WW) ? o.y : 0.f;
            o.z = (rowok && (unsigned)(cb + 2) < (unsigned)WW) ? o.z : 0.f;
            o.w = (rowok && (unsigned)(cb + 3) < (unsigned)WW) ? o.w : 0.f;
            *(float4*)(out + obase + dx * HW) = o;
        }
    }
}

extern "C" void kernel_launch(void* const* d_in, const int* in_sizes, int n_in,
                              void* d_out, int out_size, void* d_ws, size_t ws_size,
                              hipStream_t stream) {
    const float* fr = (const float*)d_in[0];
    const float* fq = (const float*)d_in[1];
    float* out = (float*)d_out;
    corr_kernel<<<dim3(NTILES * NGRP), dim3(64), 0, stream>>>(fr, fq, out);
}